// Round 16
// baseline (340.497 us; speedup 1.0000x reference)
//
#include <hip/hip_runtime.h>

typedef short bf16x8 __attribute__((ext_vector_type(8)));
typedef float f32x4 __attribute__((ext_vector_type(4)));
typedef float f32x2 __attribute__((ext_vector_type(2)));
typedef unsigned int u32x4 __attribute__((ext_vector_type(4)));

__device__ __forceinline__ unsigned short f2bf(float f) {
  unsigned int u = __float_as_uint(f);
  u = (u + 0x7FFFu + ((u >> 16) & 1u)) >> 16;  // RNE, finite data
  return (unsigned short)u;
}
__device__ __forceinline__ float bf2f(unsigned short u) {
  return __uint_as_float(((unsigned int)u) << 16);
}
__device__ __forceinline__ float silu_f(float v) {
  return v * (1.0f / (1.0f + __expf(-v)));
}
// packed f32x2 -> bf16x2 (RNE), 1 instruction
__device__ __forceinline__ unsigned int pkbf(float a, float b) {
  unsigned int r;
  asm("v_cvt_pk_bf16_f32 %0, %1, %2" : "=v"(r) : "v"(a), "v"(b));
  return r;
}
// convert pair, store to two (different-row) LDS slots
__device__ __forceinline__ void st2bf(char* base, int byA, int byB, float a, float b) {
  unsigned int p = pkbf(a, b);
  *(unsigned short*)(base + byA) = (unsigned short)p;
  *(unsigned short*)(base + byB) = (unsigned short)(p >> 16);
}

// ---------------------------------------------------------------------------
// Weight prep: bf16 conversion + per-lane fragment swizzle. Also zeroes
// hist[nzero] (folds the memset dispatch into this kernel).
// ---------------------------------------------------------------------------
__global__ void k_prep(const float* __restrict__ rW1, const float* __restrict__ rb1,
                       const float* __restrict__ rW2, const float* __restrict__ dW0,
                       const float* __restrict__ dW1, const float* __restrict__ dW2,
                       unsigned short* __restrict__ wb, int* __restrict__ hist,
                       int nzero) {
  int i = blockIdx.x * blockDim.x + threadIdx.x;
  if (i < 4096) {
    int j = i & 7, lane = (i >> 3) & 63, nt = i >> 9;
    int k = (lane >> 4) * 8 + j, n = nt * 16 + (lane & 15);
    float v = (k < 16) ? rW1[k * 128 + n] : (k == 16 ? rb1[n] : 0.0f);
    wb[i] = f2bf(v);
  } else if (i < 4096 + 4 * 16384) {
    int i2 = i - 4096, buf = i2 >> 14, r = i2 & 16383;
    int j = r & 7, lane = (r >> 3) & 63, g = r >> 9, kc = g & 3, nt = g >> 2;
    int k = kc * 32 + (lane >> 4) * 8 + j, n = nt * 16 + (lane & 15);
    const float* W = (buf == 0) ? rW2 : (buf == 1) ? dW0 : (buf == 2) ? dW1 : dW2;
    wb[4096 + buf * 16384 + r] = f2bf(W[k * 128 + n]);
  } else if (i - 69632 < nzero) {
    hist[i - 69632] = 0;
  }
}

// --------------------------- CSR construction ------------------------------
__global__ void k_hist(const int* __restrict__ ei, int* __restrict__ hist, int E) {
  int e = blockIdx.x * blockDim.x + threadIdx.x;
  if (e < E) atomicAdd(&hist[ei[E + e]], 1);
}

// Parallel scan, phase A: per-block (1024-elem) sums.
__global__ __launch_bounds__(1024) void k_scanA(const int* __restrict__ hist,
                                                int* __restrict__ part, int N) {
  __shared__ int red[1024];
  const int t = threadIdx.x;
  const int i = blockIdx.x * 1024 + t;
  red[t] = (i < N) ? hist[i] : 0;
  __syncthreads();
  for (int o = 512; o; o >>= 1) {
    if (t < o) red[t] += red[t + o];
    __syncthreads();
  }
  if (t == 0) part[blockIdx.x] = red[0];
}

// Phase C: per-block exclusive scan + cross-block offset; row_start + bump.
// bump is re-written EVERY call, so k_pos's atomics replay safely.
__global__ __launch_bounds__(1024) void k_scanC(
    const int* __restrict__ hist, const int* __restrict__ part,
    int* __restrict__ row_start, int* __restrict__ bump, int N, int nb) {
  __shared__ int sh[1024];
  __shared__ int s_off;
  const int t = threadIdx.x;
  const int b = blockIdx.x;
  if (t < 64) {
    int p = (t < nb) ? part[t] : 0;
#pragma unroll
    for (int o = 1; o < 64; o <<= 1) {
      int u = __shfl_up(p, o);
      if (t >= o) p += u;
    }
    if (b == 0) {
      if (t == 0) s_off = 0;
    } else if (t == b - 1) {
      s_off = p;
    }
  }
  __syncthreads();
  const int i = b * 1024 + t;
  const int v = (i < N) ? hist[i] : 0;
  sh[t] = v;
  __syncthreads();
  for (int o = 1; o < 1024; o <<= 1) {
    int u = (t >= o) ? sh[t - o] : 0;
    __syncthreads();
    sh[t] += u;
    __syncthreads();
  }
  const int excl = s_off + sh[t] - v;
  if (i < N) {
    row_start[i] = excl;
    bump[i] = excl;
  } else if (i == N) {
    row_start[N] = excl;
  }
}

// Inverse permutation: eidx[p] = e for CSR slot p (gtile reads Mbuf[eidx[p]]).
__global__ void k_pos(const int* __restrict__ ei, int* __restrict__ bump,
                      int* __restrict__ eidx, int E) {
  int e = blockIdx.x * blockDim.x + threadIdx.x;
  if (e < E) {
    const int p = atomicAdd(&bump[ei[E + e]], 1);
    eidx[p] = e;
  }
}

// ---------------------------------------------------------------------------
// Phase A: edge MLP + message formation, SEQUENTIAL writes:
// msg[e] = (silu(rb@rW1+rb1)@rW2 + rb2) * h[src[e]]  -> Mbuf[e] (bf16).
// Round-15 post-mortem: warm edge2 was write-bound (169MB @1.1TB/s) because
// Mbuf rows were scattered by CSR slot. Writing at slot e streams perfectly;
// the permutation moved to gtile's read side (eidx). No atomics here anymore.
// (256,2) mandatory: persistent b2f needs ~128 VGPR (rounds 8 & 12 spills).
// ---------------------------------------------------------------------------
__global__ __launch_bounds__(256, 2) void k_edge2(
    const float* __restrict__ rb, const int* __restrict__ ei,
    const float* __restrict__ h, const unsigned short* __restrict__ B1,
    const unsigned short* __restrict__ B2, const float* __restrict__ rb2,
    unsigned short* __restrict__ Mbuf, int E, int ntiles) {
  const int lane = threadIdx.x & 63;
  const int wid = threadIdx.x >> 6;
  const int kg = lane >> 4;
  const int c15 = lane & 15;
  __shared__ __align__(16) unsigned short hid[64 * 128];  // bf16, XOR-swizzled

  bf16x8 b2f[8][4];
#pragma unroll
  for (int nt = 0; nt < 8; ++nt)
#pragma unroll
    for (int kc = 0; kc < 4; ++kc)
      b2f[nt][kc] = *(const bf16x8*)(B2 + (((nt * 4 + kc) * 64 + lane) << 3));

  float rb2r[8];
#pragma unroll
  for (int nt = 0; nt < 8; ++nt) rb2r[nt] = rb2[nt * 16 + c15];

  for (int t = blockIdx.x; t < ntiles; t += gridDim.x) {
    const int ebase = t * 64 + wid * 16;

    // ---- layer 1 A-frag from global rb (K 0..15 real, 16 = bias 1.0)
    bf16x8 a1 = {};
    if (kg < 2) {
      const int e = ebase + c15;
      if (e < E) {
        const f32x4 v0 = __builtin_nontemporal_load((const f32x4*)(rb + (size_t)e * 16 + kg * 8));
        const f32x4 v1 = __builtin_nontemporal_load((const f32x4*)(rb + (size_t)e * 16 + kg * 8 + 4));
        unsigned int p0 = pkbf(v0[0], v0[1]), p1 = pkbf(v0[2], v0[3]);
        unsigned int p2 = pkbf(v1[0], v1[1]), p3 = pkbf(v1[2], v1[3]);
        a1[0] = (short)(p0 & 0xffff); a1[1] = (short)(p0 >> 16);
        a1[2] = (short)(p1 & 0xffff); a1[3] = (short)(p1 >> 16);
        a1[4] = (short)(p2 & 0xffff); a1[5] = (short)(p2 >> 16);
        a1[6] = (short)(p3 & 0xffff); a1[7] = (short)(p3 >> 16);
      }
    } else if (kg == 2) {
      a1[0] = (short)0x3F80;  // bf16 1.0 at k==16 -> adds rb1 row of B1
    }

#pragma unroll
    for (int nt = 0; nt < 8; ++nt) {
      bf16x8 b1 = *(const bf16x8*)(B1 + ((nt * 64 + lane) << 3));
      f32x4 d1 = {};
      d1 = __builtin_amdgcn_mfma_f32_16x16x32_bf16(a1, b1, d1, 0, 0, 0);
#pragma unroll
      for (int r = 0; r < 4; r += 2) {
        const int row0 = wid * 16 + kg * 4 + r;
        const int row1 = row0 + 1;
        const int col2 = (nt * 16 + c15) * 2;
        st2bf((char*)hid,
              (row0 * 256 + col2) ^ ((row0 & 7) << 4),
              (row1 * 256 + col2) ^ ((row1 & 7) << 4),
              silu_f(d1[r]), silu_f(d1[r + 1]));
      }
    }

    const int arow = wid * 16 + c15;
    f32x4 acc[8] = {};
#pragma unroll
    for (int kc = 0; kc < 4; ++kc) {
      int byt = arow * 256 + (kc * 32 + kg * 8) * 2;
      byt ^= (arow & 7) << 4;
      const bf16x8 a2 = *(const bf16x8*)((const char*)hid + byt);
#pragma unroll
      for (int nt = 0; nt < 8; ++nt)
        acc[nt] = __builtin_amdgcn_mfma_f32_16x16x32_bf16(a2, b2f[nt][kc], acc[nt], 0, 0, 0);
    }

#pragma unroll
    for (int nt = 0; nt < 8; ++nt)
#pragma unroll
      for (int r = 0; r < 4; r += 2) {
        const int row0 = wid * 16 + kg * 4 + r;
        const int row1 = row0 + 1;
        const int col2 = (nt * 16 + c15) * 2;
        st2bf((char*)hid,
              (row0 * 256 + col2) ^ ((row0 & 7) << 4),
              (row1 * 256 + col2) ^ ((row1 & 7) << 4),
              acc[nt][r] + rb2r[nt], acc[nt][r + 1] + rb2r[nt]);
      }

    // ---- repack: 8 lanes/row, gather h, write msg row at slot e (sequential)
#pragma unroll
    for (int pass = 0; pass < 2; ++pass) {
      const int ro = wid * 16 + pass * 8 + (lane >> 3);
      const int e = t * 64 + ro;
      if (e < E) {
        const int s = ei[e];
        const int cg = (lane & 7) * 16;
        const int swz = (ro & 7) << 4;
        const int bas = ro * 256 + cg * 2;
        const bf16x8 w0 = *(const bf16x8*)((const char*)hid + (bas ^ swz));
        const bf16x8 w1 = *(const bf16x8*)((const char*)hid + ((bas + 16) ^ swz));
        const f32x4* hp = (const f32x4*)(h + (size_t)s * 128 + cg);
        const f32x4 h0 = hp[0], h1 = hp[1], h2 = hp[2], h3 = hp[3];
        u32x4 m0, m1;
        m0[0] = pkbf(bf2f((unsigned short)w0[0]) * h0[0], bf2f((unsigned short)w0[1]) * h0[1]);
        m0[1] = pkbf(bf2f((unsigned short)w0[2]) * h0[2], bf2f((unsigned short)w0[3]) * h0[3]);
        m0[2] = pkbf(bf2f((unsigned short)w0[4]) * h1[0], bf2f((unsigned short)w0[5]) * h1[1]);
        m0[3] = pkbf(bf2f((unsigned short)w0[6]) * h1[2], bf2f((unsigned short)w0[7]) * h1[3]);
        m1[0] = pkbf(bf2f((unsigned short)w1[0]) * h2[0], bf2f((unsigned short)w1[1]) * h2[1]);
        m1[1] = pkbf(bf2f((unsigned short)w1[2]) * h2[2], bf2f((unsigned short)w1[3]) * h2[3]);
        m1[2] = pkbf(bf2f((unsigned short)w1[4]) * h3[0], bf2f((unsigned short)w1[5]) * h3[1]);
        m1[3] = pkbf(bf2f((unsigned short)w1[6]) * h3[2], bf2f((unsigned short)w1[7]) * h3[3]);
        *(u32x4*)(Mbuf + (size_t)e * 128 + cg) = m0;
        *(u32x4*)(Mbuf + (size_t)e * 128 + cg + 8) = m1;
      }
    }
  }
}

// ---------------------------------------------------------------------------
// Dense layer on the LDS tile (straight-line, spill-free). Rows = wid*16..+15.
// ---------------------------------------------------------------------------
__device__ __forceinline__ void dense_silu_layer(
    unsigned short* xt, const unsigned short* __restrict__ W,
    const float* __restrict__ bias, int wid, int kg, int c15, int lane) {
  const int arow = wid * 16 + c15;
  f32x4 acc[8] = {};
#pragma unroll
  for (int kc = 0; kc < 4; ++kc) {
    int byt = arow * 256 + (kc * 32 + kg * 8) * 2;
    byt ^= (arow & 7) << 4;
    const bf16x8 a2 = *(const bf16x8*)((const char*)xt + byt);
#pragma unroll
    for (int nt = 0; nt < 8; ++nt) {
      const bf16x8 bf = *(const bf16x8*)(W + (((nt * 4 + kc) * 64 + lane) << 3));
      acc[nt] = __builtin_amdgcn_mfma_f32_16x16x32_bf16(a2, bf, acc[nt], 0, 0, 0);
    }
  }
#pragma unroll
  for (int nt = 0; nt < 8; ++nt) {
    const float b = bias[nt * 16 + c15];
#pragma unroll
    for (int r = 0; r < 4; r += 2) {
      const int row0 = wid * 16 + kg * 4 + r;
      const int row1 = row0 + 1;
      const int col2 = (nt * 16 + c15) * 2;
      st2bf((char*)xt,
            (row0 * 256 + col2) ^ ((row0 & 7) << 4),
            (row1 * 256 + col2) ^ ((row1 & 7) << 4),
            silu_f(acc[nt][r] + b), silu_f(acc[nt][r + 1] + b));
    }
  }
}

// ---------------------------------------------------------------------------
// Fused gather + dense chain + output. 512 threads = 8 waves, 128-node tile,
// 4 nodes in flight per wave. Gather reads eidx[p] (contiguous) then
// Mbuf[eidx[p]] (scattered 256B rows; permutation moved to read side).
// ---------------------------------------------------------------------------
__global__ __launch_bounds__(512) void k_gtile(
    const unsigned short* __restrict__ Mbuf, const int* __restrict__ row_start,
    const int* __restrict__ eidx, const unsigned short* __restrict__ Dw,
    const float* __restrict__ db0, const float* __restrict__ db1,
    const float* __restrict__ db2, const float* __restrict__ oW,
    const float* __restrict__ ob, float* __restrict__ out, int NN, int tiles) {
  const int tid = threadIdx.x;
  const int lane = tid & 63;
  const int wid = tid >> 6;  // 0..7
  const int kg = lane >> 4;
  const int c15 = lane & 15;
  __shared__ __align__(16) unsigned short xt[128 * 128];  // 32 KB

  for (int t = blockIdx.x; t < tiles; t += gridDim.x) {
    if (t != (int)blockIdx.x) __syncthreads();
    const int rbase = wid * 16;
    const int nbase = t * 128 + rbase;

    // ---- phase 1: gather 16 nodes, 4 in flight
    for (int i = 0; i < 16; i += 4) {
      int base[4], len[4];
#pragma unroll
      for (int j = 0; j < 4; ++j) {
        const int n = nbase + i + j;
        if (n < NN) {
          const int b0 = row_start[n];
          base[j] = b0;
          len[j] = row_start[n + 1] - b0;
        } else {
          base[j] = 0;
          len[j] = 0;
        }
      }
      int maxlen = len[0] > len[1] ? len[0] : len[1];
      maxlen = maxlen > len[2] ? maxlen : len[2];
      maxlen = maxlen > len[3] ? maxlen : len[3];
      float s[4][8] = {};
      for (int off = kg; off < maxlen; off += 4) {
        int r0 = 0, r1 = 0, r2 = 0, r3 = 0;
        if (off < len[0]) r0 = eidx[base[0] + off];
        if (off < len[1]) r1 = eidx[base[1] + off];
        if (off < len[2]) r2 = eidx[base[2] + off];
        if (off < len[3]) r3 = eidx[base[3] + off];
        if (off < len[0]) {
          const bf16x8 v = *(const bf16x8*)(Mbuf + (size_t)r0 * 128 + c15 * 8);
#pragma unroll
          for (int k = 0; k < 8; ++k) s[0][k] += bf2f((unsigned short)v[k]);
        }
        if (off < len[1]) {
          const bf16x8 v = *(const bf16x8*)(Mbuf + (size_t)r1 * 128 + c15 * 8);
#pragma unroll
          for (int k = 0; k < 8; ++k) s[1][k] += bf2f((unsigned short)v[k]);
        }
        if (off < len[2]) {
          const bf16x8 v = *(const bf16x8*)(Mbuf + (size_t)r2 * 128 + c15 * 8);
#pragma unroll
          for (int k = 0; k < 8; ++k) s[2][k] += bf2f((unsigned short)v[k]);
        }
        if (off < len[3]) {
          const bf16x8 v = *(const bf16x8*)(Mbuf + (size_t)r3 * 128 + c15 * 8);
#pragma unroll
          for (int k = 0; k < 8; ++k) s[3][k] += bf2f((unsigned short)v[k]);
        }
      }
#pragma unroll
      for (int j = 0; j < 4; ++j)
#pragma unroll
        for (int k = 0; k < 8; ++k) {
          float v = s[j][k];
          v += __shfl_xor(v, 16);
          v += __shfl_xor(v, 32);
          s[j][k] = v;
        }
#pragma unroll
      for (int j = 0; j < 4; ++j) {
        if (kg == j) {
          const int n = nbase + i + j;
          if (n < NN) {
            const int row = rbase + i + j;
            u32x4 w;
            w[0] = pkbf(s[j][0], s[j][1]);
            w[1] = pkbf(s[j][2], s[j][3]);
            w[2] = pkbf(s[j][4], s[j][5]);
            w[3] = pkbf(s[j][6], s[j][7]);
            const int byt = (row * 256 + c15 * 16) ^ ((row & 7) << 4);
            *(u32x4*)((char*)xt + byt) = w;
          }
        }
      }
    }

    __syncthreads();

    // ---- phase 2: dense x3 + output dot
    dense_silu_layer(xt, Dw, db0, wid, kg, c15, lane);
    dense_silu_layer(xt, Dw + 16384, db1, wid, kg, c15, lane);

    {
      const int arow = wid * 16 + c15;
      const unsigned short* W = Dw + 32768;
      f32x4 acc[8] = {};
#pragma unroll
      for (int kc = 0; kc < 4; ++kc) {
        int byt = arow * 256 + (kc * 32 + kg * 8) * 2;
        byt ^= (arow & 7) << 4;
        const bf16x8 a2 = *(const bf16x8*)((const char*)xt + byt);
#pragma unroll
        for (int nt = 0; nt < 8; ++nt) {
          const bf16x8 bf = *(const bf16x8*)(W + (((nt * 4 + kc) * 64 + lane) << 3));
          acc[nt] = __builtin_amdgcn_mfma_f32_16x16x32_bf16(a2, bf, acc[nt], 0, 0, 0);
        }
      }
      const float obv = ob[0];
#pragma unroll
      for (int r = 0; r < 4; ++r) {
        float p = 0.f;
#pragma unroll
        for (int nt = 0; nt < 8; ++nt) {
          const float b = db2[nt * 16 + c15];
          p += silu_f(acc[nt][r] + b) * oW[nt * 16 + c15];
        }
        p += __shfl_xor(p, 1);
        p += __shfl_xor(p, 2);
        p += __shfl_xor(p, 4);
        p += __shfl_xor(p, 8);
        const int n = nbase + kg * 4 + r;
        if (c15 == 0 && n < NN) out[n] = p + obv;
      }
    }
  }
}

// ---------------------------------------------------------------------------
// Fallback path kernels (atomic scatter + separate dense/out).
// ---------------------------------------------------------------------------
__global__ __launch_bounds__(256, 2) void k_edge(
    const float* __restrict__ rb, const int* __restrict__ ei,
    const float* __restrict__ h, const unsigned short* __restrict__ B1,
    const unsigned short* __restrict__ B2, const float* __restrict__ rb2,
    float* __restrict__ x, int E, int ntiles) {
  const int lane = threadIdx.x & 63;
  const int wid = threadIdx.x >> 6;
  const int kg = lane >> 4;
  const int c15 = lane & 15;
  __shared__ __align__(16) unsigned short hid[64 * 128];

  bf16x8 b2f[8][4];
#pragma unroll
  for (int nt = 0; nt < 8; ++nt)
#pragma unroll
    for (int kc = 0; kc < 4; ++kc)
      b2f[nt][kc] = *(const bf16x8*)(B2 + (((nt * 4 + kc) * 64 + lane) << 3));

  float rb2r[8];
#pragma unroll
  for (int nt = 0; nt < 8; ++nt) rb2r[nt] = rb2[nt * 16 + c15];

  for (int t = blockIdx.x; t < ntiles; t += gridDim.x) {
    const int ebase = t * 64 + wid * 16;
    bf16x8 a1 = {};
    if (kg < 2) {
      const int e = ebase + c15;
      if (e < E) {
        const f32x4 v0 = *(const f32x4*)(rb + (size_t)e * 16 + kg * 8);
        const f32x4 v1 = *(const f32x4*)(rb + (size_t)e * 16 + kg * 8 + 4);
        a1[0] = (short)f2bf(v0[0]); a1[1] = (short)f2bf(v0[1]);
        a1[2] = (short)f2bf(v0[2]); a1[3] = (short)f2bf(v0[3]);
        a1[4] = (short)f2bf(v1[0]); a1[5] = (short)f2bf(v1[1]);
        a1[6] = (short)f2bf(v1[2]); a1[7] = (short)f2bf(v1[3]);
      }
    } else if (kg == 2) {
      a1[0] = (short)0x3F80;
    }
#pragma unroll
    for (int nt = 0; nt < 8; ++nt) {
      bf16x8 b1 = *(const bf16x8*)(B1 + ((nt * 64 + lane) << 3));
      f32x4 d1 = {};
      d1 = __builtin_amdgcn_mfma_f32_16x16x32_bf16(a1, b1, d1, 0, 0, 0);
#pragma unroll
      for (int r = 0; r < 4; ++r) {
        const int row = wid * 16 + kg * 4 + r;
        int byt = row * 256 + (nt * 16 + c15) * 2;
        byt ^= (row & 7) << 4;
        *(unsigned short*)((char*)hid + byt) = f2bf(silu_f(d1[r]));
      }
    }
    const int arow = wid * 16 + c15;
    f32x4 acc[8] = {};
#pragma unroll
    for (int kc = 0; kc < 4; ++kc) {
      int byt = arow * 256 + (kc * 32 + kg * 8) * 2;
      byt ^= (arow & 7) << 4;
      const bf16x8 a2 = *(const bf16x8*)((const char*)hid + byt);
#pragma unroll
      for (int nt = 0; nt < 8; ++nt)
        acc[nt] = __builtin_amdgcn_mfma_f32_16x16x32_bf16(a2, b2f[nt][kc], acc[nt], 0, 0, 0);
    }
#pragma unroll
    for (int r = 0; r < 4; ++r) {
      const int e = ebase + kg * 4 + r;
      if (e < E) {
        const int s = ei[e];
        const int d = ei[E + e];
#pragma unroll
        for (int nt = 0; nt < 8; ++nt) {
          const int col = nt * 16 + c15;
          const float w = acc[nt][r] + rb2r[nt];
          const float hv = h[(size_t)s * 128 + col];
          atomicAdd(x + (size_t)d * 128 + col, w * hv);
        }
      }
    }
  }
}

__global__ __launch_bounds__(256, 2) void k_dense(
    float* __restrict__ x, const unsigned short* __restrict__ Bw,
    const float* __restrict__ bias, int M) {
  const int lane = threadIdx.x & 63;
  const int wid = threadIdx.x >> 6;
  const int kg = lane >> 4;
  const int c15 = lane & 15;

  bf16x8 bf[8][4];
#pragma unroll
  for (int nt = 0; nt < 8; ++nt)
#pragma unroll
    for (int kc = 0; kc < 4; ++kc)
      bf[nt][kc] = *(const bf16x8*)(Bw + (((nt * 4 + kc) * 64 + lane) << 3));

  float br[8];
#pragma unroll
  for (int nt = 0; nt < 8; ++nt) br[nt] = bias[nt * 16 + c15];

  const int tiles = (M + 63) >> 6;
  for (int t = blockIdx.x; t < tiles; t += gridDim.x) {
    const int rbase = t * 64 + wid * 16;
    const int row = rbase + c15;
    bf16x8 a[4];
#pragma unroll
    for (int kc = 0; kc < 4; ++kc) {
      bf16x8 az = {};
      if (row < M) {
        const f32x4 v0 = *(const f32x4*)(x + (size_t)row * 128 + kc * 32 + kg * 8);
        const f32x4 v1 = *(const f32x4*)(x + (size_t)row * 128 + kc * 32 + kg * 8 + 4);
        az[0] = (short)f2bf(v0[0]); az[1] = (short)f2bf(v0[1]);
        az[2] = (short)f2bf(v0[2]); az[3] = (short)f2bf(v0[3]);
        az[4] = (short)f2bf(v1[0]); az[5] = (short)f2bf(v1[1]);
        az[6] = (short)f2bf(v1[2]); az[7] = (short)f2bf(v1[3]);
      }
      a[kc] = az;
    }
    f32x4 acc[8] = {};
#pragma unroll
    for (int kc = 0; kc < 4; ++kc)
#pragma unroll
      for (int nt = 0; nt < 8; ++nt)
        acc[nt] = __builtin_amdgcn_mfma_f32_16x16x32_bf16(a[kc], bf[nt][kc], acc[nt], 0, 0, 0);
#pragma unroll
    for (int r = 0; r < 4; ++r) {
      const int orow = rbase + kg * 4 + r;
      if (orow < M) {
#pragma unroll
        for (int nt = 0; nt < 8; ++nt)
          x[(size_t)orow * 128 + nt * 16 + c15] = silu_f(acc[nt][r] + br[nt]);
      }
    }
  }
}

__global__ void k_out(const float* __restrict__ x, const float* __restrict__ oW,
                      const float* __restrict__ ob, float* __restrict__ out, int M) {
  const int lane = threadIdx.x & 63;
  const int w = (int)((blockIdx.x * blockDim.x + threadIdx.x) >> 6);
  const int nw = (int)((gridDim.x * blockDim.x) >> 6);
  const float w0 = oW[lane], w1 = oW[64 + lane];
  const float obv = ob[0];
  for (int row = w; row < M; row += nw) {
    float a = x[(size_t)row * 128 + lane] * w0 + x[(size_t)row * 128 + 64 + lane] * w1;
#pragma unroll
    for (int m = 32; m; m >>= 1) a += __shfl_xor(a, m);
    if (lane == 0) out[row] = a + obv;
  }
}

// ---------------------------------------------------------------------------
extern "C" void kernel_launch(void* const* d_in, const int* in_sizes, int n_in,
                              void* d_out, int out_size, void* d_ws, size_t ws_size,
                              hipStream_t stream) {
  const float* h   = (const float*)d_in[0];
  const float* rb  = (const float*)d_in[1];
  const int*   ei  = (const int*)d_in[2];
  const float* rW1 = (const float*)d_in[3];
  const float* rb1 = (const float*)d_in[4];
  const float* rW2 = (const float*)d_in[5];
  const float* rb2 = (const float*)d_in[6];
  const float* dW0 = (const float*)d_in[7];
  const float* db0 = (const float*)d_in[8];
  const float* dW1 = (const float*)d_in[9];
  const float* db1 = (const float*)d_in[10];
  const float* dW2 = (const float*)d_in[11];
  const float* db2 = (const float*)d_in[12];
  const float* oW  = (const float*)d_in[13];
  const float* ob  = (const float*)d_in[14];

  const int NN = in_sizes[0] / 128;  // 50000 nodes
  const int E  = in_sizes[1] / 16;   // 600000 edges

  char* base = (char*)d_ws;
  size_t off = 0;
  auto alloc = [&](size_t bytes) {
    char* p = base + off;
    off += (bytes + 255) & ~(size_t)255;
    return p;
  };
  float* x            = (float*)alloc((size_t)NN * 128 * 4);  // fallback only
  unsigned short* wb  = (unsigned short*)alloc((size_t)69632 * 2);
  int* row_start      = (int*)alloc((size_t)(NN + 1) * 4);
  int* hist           = (int*)alloc((size_t)NN * 4);
  int* bump           = (int*)alloc((size_t)NN * 4);
  int* part           = (int*)alloc((size_t)64 * 4);
  int* eidx           = (int*)alloc((size_t)E * 4);
  unsigned short* Mb  = (unsigned short*)alloc((size_t)E * 256);
  const bool fits = off <= ws_size && NN <= 65535;

  const int ntiles = (E + 63) / 64;
  const int gE = (E + 255) / 256;
  const int nb = (NN + 1023) / 1024;

  if (fits) {
    k_prep<<<(69632 + NN + 255) / 256, 256, 0, stream>>>(rW1, rb1, rW2, dW0, dW1,
                                                         dW2, wb, hist, NN);
    const int eg = ntiles < 2048 ? ntiles : 2048;
    k_edge2<<<eg, 256, 0, stream>>>(rb, ei, h, wb, wb + 4096, rb2, Mb, E, ntiles);
    k_hist<<<gE, 256, 0, stream>>>(ei, hist, E);
    k_scanA<<<nb, 1024, 0, stream>>>(hist, part, NN);
    k_scanC<<<nb, 1024, 0, stream>>>(hist, part, row_start, bump, NN, nb);
    k_pos<<<gE, 256, 0, stream>>>(ei, bump, eidx, E);
    const int gt = (NN + 127) / 128;
    k_gtile<<<gt, 512, 0, stream>>>(Mb, row_start, eidx, wb + 20480, db0, db1,
                                    db2, oW, ob, (float*)d_out, NN, gt);
  } else {
    k_prep<<<(69632 + 255) / 256, 256, 0, stream>>>(rW1, rb1, rW2, dW0, dW1,
                                                    dW2, wb, hist, 0);
    hipMemsetAsync(x, 0, (size_t)NN * 512, stream);
    const int eg = ntiles < 1024 ? ntiles : 1024;
    k_edge<<<eg, 256, 0, stream>>>(rb, ei, h, wb, wb + 4096, rb2, x, E, ntiles);
    k_dense<<<512, 256, 0, stream>>>(x, wb + 20480, db0, NN);
    k_dense<<<512, 256, 0, stream>>>(x, wb + 36864, db1, NN);
    k_dense<<<512, 256, 0, stream>>>(x, wb + 53248, db2, NN);
    k_out<<<512, 256, 0, stream>>>(x, oW, ob, (float*)d_out, NN);
  }
}

// Round 17
// 281.981 us; speedup vs baseline: 1.2075x; 1.2075x over previous
//
#include <hip/hip_runtime.h>

typedef short bf16x8 __attribute__((ext_vector_type(8)));
typedef float f32x4 __attribute__((ext_vector_type(4)));
typedef float f32x2 __attribute__((ext_vector_type(2)));
typedef unsigned int u32x4 __attribute__((ext_vector_type(4)));

__device__ __forceinline__ unsigned short f2bf(float f) {
  unsigned int u = __float_as_uint(f);
  u = (u + 0x7FFFu + ((u >> 16) & 1u)) >> 16;  // RNE, finite data
  return (unsigned short)u;
}
__device__ __forceinline__ float bf2f(unsigned short u) {
  return __uint_as_float(((unsigned int)u) << 16);
}
__device__ __forceinline__ float silu_f(float v) {
  return v * (1.0f / (1.0f + __expf(-v)));
}
// packed f32x2 -> bf16x2 (RNE), 1 instruction
__device__ __forceinline__ unsigned int pkbf(float a, float b) {
  unsigned int r;
  asm("v_cvt_pk_bf16_f32 %0, %1, %2" : "=v"(r) : "v"(a), "v"(b));
  return r;
}
// convert pair, store to two (different-row) LDS slots
__device__ __forceinline__ void st2bf(char* base, int byA, int byB, float a, float b) {
  unsigned int p = pkbf(a, b);
  *(unsigned short*)(base + byA) = (unsigned short)p;
  *(unsigned short*)(base + byB) = (unsigned short)(p >> 16);
}

// ---------------------------------------------------------------------------
// Weight prep: bf16 conversion + per-lane fragment swizzle. Also zeroes
// hist[nzero] (folds the memset dispatch into this kernel).
// ---------------------------------------------------------------------------
__global__ void k_prep(const float* __restrict__ rW1, const float* __restrict__ rb1,
                       const float* __restrict__ rW2, const float* __restrict__ dW0,
                       const float* __restrict__ dW1, const float* __restrict__ dW2,
                       unsigned short* __restrict__ wb, int* __restrict__ hist,
                       int nzero) {
  int i = blockIdx.x * blockDim.x + threadIdx.x;
  if (i < 4096) {
    int j = i & 7, lane = (i >> 3) & 63, nt = i >> 9;
    int k = (lane >> 4) * 8 + j, n = nt * 16 + (lane & 15);
    float v = (k < 16) ? rW1[k * 128 + n] : (k == 16 ? rb1[n] : 0.0f);
    wb[i] = f2bf(v);
  } else if (i < 4096 + 4 * 16384) {
    int i2 = i - 4096, buf = i2 >> 14, r = i2 & 16383;
    int j = r & 7, lane = (r >> 3) & 63, g = r >> 9, kc = g & 3, nt = g >> 2;
    int k = kc * 32 + (lane >> 4) * 8 + j, n = nt * 16 + (lane & 15);
    const float* W = (buf == 0) ? rW2 : (buf == 1) ? dW0 : (buf == 2) ? dW1 : dW2;
    wb[4096 + buf * 16384 + r] = f2bf(W[k * 128 + n]);
  } else if (i - 69632 < nzero) {
    hist[i - 69632] = 0;
  }
}

// --------------------------- CSR construction ------------------------------
__global__ void k_hist(const int* __restrict__ ei, int* __restrict__ hist, int E) {
  int e = blockIdx.x * blockDim.x + threadIdx.x;
  if (e < E) atomicAdd(&hist[ei[E + e]], 1);
}

// Parallel scan, phase A: per-block (1024-elem) sums.
__global__ __launch_bounds__(1024) void k_scanA(const int* __restrict__ hist,
                                                int* __restrict__ part, int N) {
  __shared__ int red[1024];
  const int t = threadIdx.x;
  const int i = blockIdx.x * 1024 + t;
  red[t] = (i < N) ? hist[i] : 0;
  __syncthreads();
  for (int o = 512; o; o >>= 1) {
    if (t < o) red[t] += red[t + o];
    __syncthreads();
  }
  if (t == 0) part[blockIdx.x] = red[0];
}

// Phase C: per-block exclusive scan + cross-block offset; row_start + bump.
// bump is re-written EVERY call, so edge2's in-place bump atomics replay safely.
__global__ __launch_bounds__(1024) void k_scanC(
    const int* __restrict__ hist, const int* __restrict__ part,
    int* __restrict__ row_start, int* __restrict__ bump, int N, int nb) {
  __shared__ int sh[1024];
  __shared__ int s_off;
  const int t = threadIdx.x;
  const int b = blockIdx.x;
  if (t < 64) {
    int p = (t < nb) ? part[t] : 0;
#pragma unroll
    for (int o = 1; o < 64; o <<= 1) {
      int u = __shfl_up(p, o);
      if (t >= o) p += u;
    }
    if (b == 0) {
      if (t == 0) s_off = 0;
    } else if (t == b - 1) {
      s_off = p;
    }
  }
  __syncthreads();
  const int i = b * 1024 + t;
  const int v = (i < N) ? hist[i] : 0;
  sh[t] = v;
  __syncthreads();
  for (int o = 1; o < 1024; o <<= 1) {
    int u = (t >= o) ? sh[t - o] : 0;
    __syncthreads();
    sh[t] += u;
    __syncthreads();
  }
  const int excl = s_off + sh[t] - v;
  if (i < N) {
    row_start[i] = excl;
    bump[i] = excl;
  } else if (i == N) {
    row_start[N] = excl;
  }
}

// ---------------------------------------------------------------------------
// Phase A: edge MLP + message formation, scatter-free (write to CSR slot).
// msg[e] = (silu(rb@rW1+rb1)@rW2 + rb2) * h[src[e]]  -> Mbuf[slot].
// Round-17: B2 weights moved VGPR -> LDS (32KB staged once per block). This
// frees ~128 VGPRs so (256,3) no longer spills (cap 85), raising occupancy
// 2 -> 3 waves/SIMD (LDS-limited: 48KB/block -> 3 blocks/CU). Slot claim
// stays hoisted to tile start (T14). Scatter stays on WRITE side (round-16
// showed read-side indirection is worse: gtile 100 -> 156us).
// ---------------------------------------------------------------------------
__global__ __launch_bounds__(256, 3) void k_edge2(
    const float* __restrict__ rb, const int* __restrict__ ei,
    const float* __restrict__ h, const unsigned short* __restrict__ B1,
    const unsigned short* __restrict__ B2, const float* __restrict__ rb2,
    int* __restrict__ bump, unsigned short* __restrict__ Mbuf,
    int E, int ntiles) {
  const int tid = threadIdx.x;
  const int lane = tid & 63;
  const int wid = tid >> 6;
  const int kg = lane >> 4;
  const int c15 = lane & 15;
  __shared__ __align__(16) unsigned short hid[64 * 128];   // 16 KB msg tile
  __shared__ __align__(16) unsigned short B2s[16384];      // 32 KB B2 weights

  // ---- stage B2 into LDS (once per block), fragment order preserved
#pragma unroll
  for (int i = 0; i < 8; ++i) {
    const int c = tid + i * 256;  // 2048 chunks of 8 ushorts
    *(bf16x8*)(B2s + (c << 3)) = *(const bf16x8*)(B2 + (c << 3));
  }
  __syncthreads();

  float rb2r[8];
#pragma unroll
  for (int nt = 0; nt < 8; ++nt) rb2r[nt] = rb2[nt * 16 + c15];

  for (int t = blockIdx.x; t < ntiles; t += gridDim.x) {
    const int ebase = t * 64 + wid * 16;

    // ---- early slot claim: ei loads + atomic + broadcast, overlapped with MLP
    int sP[2], pP[2];
#pragma unroll
    for (int pass = 0; pass < 2; ++pass) {
      const int ro8 = pass * 8 + (lane >> 3);
      const int e2 = t * 64 + wid * 16 + ro8;
      int pc = 0;
      sP[pass] = 0;
      if (e2 < E) {
        sP[pass] = ei[e2];
        const int d = ei[E + e2];
        if ((lane & 7) == 0) pc = atomicAdd(&bump[d], 1);
      }
      pP[pass] = __shfl(pc, lane & 56);
    }

    // ---- layer 1 A-frag from global rb (K 0..15 real, 16 = bias 1.0)
    bf16x8 a1 = {};
    if (kg < 2) {
      const int e = ebase + c15;
      if (e < E) {
        const f32x4 v0 = __builtin_nontemporal_load((const f32x4*)(rb + (size_t)e * 16 + kg * 8));
        const f32x4 v1 = __builtin_nontemporal_load((const f32x4*)(rb + (size_t)e * 16 + kg * 8 + 4));
        unsigned int p0 = pkbf(v0[0], v0[1]), p1 = pkbf(v0[2], v0[3]);
        unsigned int p2 = pkbf(v1[0], v1[1]), p3 = pkbf(v1[2], v1[3]);
        a1[0] = (short)(p0 & 0xffff); a1[1] = (short)(p0 >> 16);
        a1[2] = (short)(p1 & 0xffff); a1[3] = (short)(p1 >> 16);
        a1[4] = (short)(p2 & 0xffff); a1[5] = (short)(p2 >> 16);
        a1[6] = (short)(p3 & 0xffff); a1[7] = (short)(p3 >> 16);
      }
    } else if (kg == 2) {
      a1[0] = (short)0x3F80;  // bf16 1.0 at k==16 -> adds rb1 row of B1
    }

#pragma unroll
    for (int nt = 0; nt < 8; ++nt) {
      bf16x8 b1 = *(const bf16x8*)(B1 + ((nt * 64 + lane) << 3));
      f32x4 d1 = {};
      d1 = __builtin_amdgcn_mfma_f32_16x16x32_bf16(a1, b1, d1, 0, 0, 0);
#pragma unroll
      for (int r = 0; r < 4; r += 2) {
        const int row0 = wid * 16 + kg * 4 + r;
        const int row1 = row0 + 1;
        const int col2 = (nt * 16 + c15) * 2;
        st2bf((char*)hid,
              (row0 * 256 + col2) ^ ((row0 & 7) << 4),
              (row1 * 256 + col2) ^ ((row1 & 7) << 4),
              silu_f(d1[r]), silu_f(d1[r + 1]));
      }
    }

    // ---- layer 2: A from LDS, B from LDS (lane-strided b128, conflict-free)
    const int arow = wid * 16 + c15;
    f32x4 acc[8] = {};
#pragma unroll
    for (int kc = 0; kc < 4; ++kc) {
      int byt = arow * 256 + (kc * 32 + kg * 8) * 2;
      byt ^= (arow & 7) << 4;
      const bf16x8 a2 = *(const bf16x8*)((const char*)hid + byt);
#pragma unroll
      for (int nt = 0; nt < 8; ++nt) {
        const bf16x8 bf = *(const bf16x8*)(B2s + (((nt * 4 + kc) * 64 + lane) << 3));
        acc[nt] = __builtin_amdgcn_mfma_f32_16x16x32_bf16(a2, bf, acc[nt], 0, 0, 0);
      }
    }

#pragma unroll
    for (int nt = 0; nt < 8; ++nt)
#pragma unroll
      for (int r = 0; r < 4; r += 2) {
        const int row0 = wid * 16 + kg * 4 + r;
        const int row1 = row0 + 1;
        const int col2 = (nt * 16 + c15) * 2;
        st2bf((char*)hid,
              (row0 * 256 + col2) ^ ((row0 & 7) << 4),
              (row1 * 256 + col2) ^ ((row1 & 7) << 4),
              acc[nt][r] + rb2r[nt], acc[nt][r + 1] + rb2r[nt]);
      }

#pragma unroll
    for (int pass = 0; pass < 2; ++pass) {
      const int ro = wid * 16 + pass * 8 + (lane >> 3);
      const int e = t * 64 + ro;
      if (e < E) {
        const int p = pP[pass];
        const int s = sP[pass];
        const int cg = (lane & 7) * 16;
        const int swz = (ro & 7) << 4;
        const int bas = ro * 256 + cg * 2;
        const bf16x8 w0 = *(const bf16x8*)((const char*)hid + (bas ^ swz));
        const bf16x8 w1 = *(const bf16x8*)((const char*)hid + ((bas + 16) ^ swz));
        const f32x4* hp = (const f32x4*)(h + (size_t)s * 128 + cg);
        const f32x4 h0 = hp[0], h1 = hp[1], h2 = hp[2], h3 = hp[3];
        u32x4 m0, m1;
        m0[0] = pkbf(bf2f((unsigned short)w0[0]) * h0[0], bf2f((unsigned short)w0[1]) * h0[1]);
        m0[1] = pkbf(bf2f((unsigned short)w0[2]) * h0[2], bf2f((unsigned short)w0[3]) * h0[3]);
        m0[2] = pkbf(bf2f((unsigned short)w0[4]) * h1[0], bf2f((unsigned short)w0[5]) * h1[1]);
        m0[3] = pkbf(bf2f((unsigned short)w0[6]) * h1[2], bf2f((unsigned short)w0[7]) * h1[3]);
        m1[0] = pkbf(bf2f((unsigned short)w1[0]) * h2[0], bf2f((unsigned short)w1[1]) * h2[1]);
        m1[1] = pkbf(bf2f((unsigned short)w1[2]) * h2[2], bf2f((unsigned short)w1[3]) * h2[3]);
        m1[2] = pkbf(bf2f((unsigned short)w1[4]) * h3[0], bf2f((unsigned short)w1[5]) * h3[1]);
        m1[3] = pkbf(bf2f((unsigned short)w1[6]) * h3[2], bf2f((unsigned short)w1[7]) * h3[3]);
        *(u32x4*)(Mbuf + (size_t)p * 128 + cg) = m0;
        *(u32x4*)(Mbuf + (size_t)p * 128 + cg + 8) = m1;
      }
    }
  }
}

// ---------------------------------------------------------------------------
// Dense layer on the LDS tile (straight-line, spill-free). Rows = wid*16..+15.
// ---------------------------------------------------------------------------
__device__ __forceinline__ void dense_silu_layer(
    unsigned short* xt, const unsigned short* __restrict__ W,
    const float* __restrict__ bias, int wid, int kg, int c15, int lane) {
  const int arow = wid * 16 + c15;
  f32x4 acc[8] = {};
#pragma unroll
  for (int kc = 0; kc < 4; ++kc) {
    int byt = arow * 256 + (kc * 32 + kg * 8) * 2;
    byt ^= (arow & 7) << 4;
    const bf16x8 a2 = *(const bf16x8*)((const char*)xt + byt);
#pragma unroll
    for (int nt = 0; nt < 8; ++nt) {
      const bf16x8 bf = *(const bf16x8*)(W + (((nt * 4 + kc) * 64 + lane) << 3));
      acc[nt] = __builtin_amdgcn_mfma_f32_16x16x32_bf16(a2, bf, acc[nt], 0, 0, 0);
    }
  }
#pragma unroll
  for (int nt = 0; nt < 8; ++nt) {
    const float b = bias[nt * 16 + c15];
#pragma unroll
    for (int r = 0; r < 4; r += 2) {
      const int row0 = wid * 16 + kg * 4 + r;
      const int row1 = row0 + 1;
      const int col2 = (nt * 16 + c15) * 2;
      st2bf((char*)xt,
            (row0 * 256 + col2) ^ ((row0 & 7) << 4),
            (row1 * 256 + col2) ^ ((row1 & 7) << 4),
            silu_f(acc[nt][r] + b), silu_f(acc[nt][r + 1] + b));
    }
  }
}

// ---------------------------------------------------------------------------
// Fused gather + dense chain + output. 512 threads = 8 waves, 128-node tile,
// 4 nodes in flight per wave (proven shape; 8-in-flight spills, 256t is
// occupancy-bound). Contiguous CSR reads (Mbuf is in CSR slot order).
// ---------------------------------------------------------------------------
__global__ __launch_bounds__(512) void k_gtile(
    const unsigned short* __restrict__ Mbuf, const int* __restrict__ row_start,
    const unsigned short* __restrict__ Dw, const float* __restrict__ db0,
    const float* __restrict__ db1, const float* __restrict__ db2,
    const float* __restrict__ oW, const float* __restrict__ ob,
    float* __restrict__ out, int NN, int tiles) {
  const int tid = threadIdx.x;
  const int lane = tid & 63;
  const int wid = tid >> 6;  // 0..7
  const int kg = lane >> 4;
  const int c15 = lane & 15;
  __shared__ __align__(16) unsigned short xt[128 * 128];  // 32 KB

  for (int t = blockIdx.x; t < tiles; t += gridDim.x) {
    if (t != (int)blockIdx.x) __syncthreads();
    const int rbase = wid * 16;
    const int nbase = t * 128 + rbase;

    // ---- phase 1: gather 16 nodes, 4 in flight
    for (int i = 0; i < 16; i += 4) {
      int base[4], len[4];
#pragma unroll
      for (int j = 0; j < 4; ++j) {
        const int n = nbase + i + j;
        if (n < NN) {
          const int b0 = row_start[n];
          base[j] = b0;
          len[j] = row_start[n + 1] - b0;
        } else {
          base[j] = 0;
          len[j] = 0;
        }
      }
      int maxlen = len[0] > len[1] ? len[0] : len[1];
      maxlen = maxlen > len[2] ? maxlen : len[2];
      maxlen = maxlen > len[3] ? maxlen : len[3];
      float s[4][8] = {};
      for (int off = kg; off < maxlen; off += 4) {
#pragma unroll
        for (int j = 0; j < 4; ++j) {
          if (off < len[j]) {
            const bf16x8 v = *(const bf16x8*)(Mbuf + (size_t)(base[j] + off) * 128 + c15 * 8);
#pragma unroll
            for (int k = 0; k < 8; ++k) s[j][k] += bf2f((unsigned short)v[k]);
          }
        }
      }
#pragma unroll
      for (int j = 0; j < 4; ++j)
#pragma unroll
        for (int k = 0; k < 8; ++k) {
          float v = s[j][k];
          v += __shfl_xor(v, 16);
          v += __shfl_xor(v, 32);
          s[j][k] = v;
        }
#pragma unroll
      for (int j = 0; j < 4; ++j) {
        if (kg == j) {
          const int n = nbase + i + j;
          if (n < NN) {
            const int row = rbase + i + j;
            u32x4 w;
            w[0] = pkbf(s[j][0], s[j][1]);
            w[1] = pkbf(s[j][2], s[j][3]);
            w[2] = pkbf(s[j][4], s[j][5]);
            w[3] = pkbf(s[j][6], s[j][7]);
            const int byt = (row * 256 + c15 * 16) ^ ((row & 7) << 4);
            *(u32x4*)((char*)xt + byt) = w;
          }
        }
      }
    }

    __syncthreads();

    // ---- phase 2: dense x3 + output dot
    dense_silu_layer(xt, Dw, db0, wid, kg, c15, lane);
    dense_silu_layer(xt, Dw + 16384, db1, wid, kg, c15, lane);

    {
      const int arow = wid * 16 + c15;
      const unsigned short* W = Dw + 32768;
      f32x4 acc[8] = {};
#pragma unroll
      for (int kc = 0; kc < 4; ++kc) {
        int byt = arow * 256 + (kc * 32 + kg * 8) * 2;
        byt ^= (arow & 7) << 4;
        const bf16x8 a2 = *(const bf16x8*)((const char*)xt + byt);
#pragma unroll
        for (int nt = 0; nt < 8; ++nt) {
          const bf16x8 bf = *(const bf16x8*)(W + (((nt * 4 + kc) * 64 + lane) << 3));
          acc[nt] = __builtin_amdgcn_mfma_f32_16x16x32_bf16(a2, bf, acc[nt], 0, 0, 0);
        }
      }
      const float obv = ob[0];
#pragma unroll
      for (int r = 0; r < 4; ++r) {
        float p = 0.f;
#pragma unroll
        for (int nt = 0; nt < 8; ++nt) {
          const float b = db2[nt * 16 + c15];
          p += silu_f(acc[nt][r] + b) * oW[nt * 16 + c15];
        }
        p += __shfl_xor(p, 1);
        p += __shfl_xor(p, 2);
        p += __shfl_xor(p, 4);
        p += __shfl_xor(p, 8);
        const int n = nbase + kg * 4 + r;
        if (c15 == 0 && n < NN) out[n] = p + obv;
      }
    }
  }
}

// ---------------------------------------------------------------------------
// Fallback path kernels (atomic scatter + separate dense/out).
// ---------------------------------------------------------------------------
__global__ __launch_bounds__(256, 2) void k_edge(
    const float* __restrict__ rb, const int* __restrict__ ei,
    const float* __restrict__ h, const unsigned short* __restrict__ B1,
    const unsigned short* __restrict__ B2, const float* __restrict__ rb2,
    float* __restrict__ x, int E, int ntiles) {
  const int lane = threadIdx.x & 63;
  const int wid = threadIdx.x >> 6;
  const int kg = lane >> 4;
  const int c15 = lane & 15;
  __shared__ __align__(16) unsigned short hid[64 * 128];

  bf16x8 b2f[8][4];
#pragma unroll
  for (int nt = 0; nt < 8; ++nt)
#pragma unroll
    for (int kc = 0; kc < 4; ++kc)
      b2f[nt][kc] = *(const bf16x8*)(B2 + (((nt * 4 + kc) * 64 + lane) << 3));

  float rb2r[8];
#pragma unroll
  for (int nt = 0; nt < 8; ++nt) rb2r[nt] = rb2[nt * 16 + c15];

  for (int t = blockIdx.x; t < ntiles; t += gridDim.x) {
    const int ebase = t * 64 + wid * 16;
    bf16x8 a1 = {};
    if (kg < 2) {
      const int e = ebase + c15;
      if (e < E) {
        const f32x4 v0 = *(const f32x4*)(rb + (size_t)e * 16 + kg * 8);
        const f32x4 v1 = *(const f32x4*)(rb + (size_t)e * 16 + kg * 8 + 4);
        a1[0] = (short)f2bf(v0[0]); a1[1] = (short)f2bf(v0[1]);
        a1[2] = (short)f2bf(v0[2]); a1[3] = (short)f2bf(v0[3]);
        a1[4] = (short)f2bf(v1[0]); a1[5] = (short)f2bf(v1[1]);
        a1[6] = (short)f2bf(v1[2]); a1[7] = (short)f2bf(v1[3]);
      }
    } else if (kg == 2) {
      a1[0] = (short)0x3F80;
    }
#pragma unroll
    for (int nt = 0; nt < 8; ++nt) {
      bf16x8 b1 = *(const bf16x8*)(B1 + ((nt * 64 + lane) << 3));
      f32x4 d1 = {};
      d1 = __builtin_amdgcn_mfma_f32_16x16x32_bf16(a1, b1, d1, 0, 0, 0);
#pragma unroll
      for (int r = 0; r < 4; ++r) {
        const int row = wid * 16 + kg * 4 + r;
        int byt = row * 256 + (nt * 16 + c15) * 2;
        byt ^= (row & 7) << 4;
        *(unsigned short*)((char*)hid + byt) = f2bf(silu_f(d1[r]));
      }
    }
    const int arow = wid * 16 + c15;
    f32x4 acc[8] = {};
#pragma unroll
    for (int kc = 0; kc < 4; ++kc) {
      int byt = arow * 256 + (kc * 32 + kg * 8) * 2;
      byt ^= (arow & 7) << 4;
      const bf16x8 a2 = *(const bf16x8*)((const char*)hid + byt);
#pragma unroll
      for (int nt = 0; nt < 8; ++nt)
        acc[nt] = __builtin_amdgcn_mfma_f32_16x16x32_bf16(a2, b2f[nt][kc], acc[nt], 0, 0, 0);
    }
#pragma unroll
    for (int r = 0; r < 4; ++r) {
      const int e = ebase + kg * 4 + r;
      if (e < E) {
        const int s = ei[e];
        const int d = ei[E + e];
#pragma unroll
        for (int nt = 0; nt < 8; ++nt) {
          const int col = nt * 16 + c15;
          const float w = acc[nt][r] + rb2r[nt];
          const float hv = h[(size_t)s * 128 + col];
          atomicAdd(x + (size_t)d * 128 + col, w * hv);
        }
      }
    }
  }
}

__global__ __launch_bounds__(256, 2) void k_dense(
    float* __restrict__ x, const unsigned short* __restrict__ Bw,
    const float* __restrict__ bias, int M) {
  const int lane = threadIdx.x & 63;
  const int wid = threadIdx.x >> 6;
  const int kg = lane >> 4;
  const int c15 = lane & 15;

  bf16x8 bf[8][4];
#pragma unroll
  for (int nt = 0; nt < 8; ++nt)
#pragma unroll
    for (int kc = 0; kc < 4; ++kc)
      bf[nt][kc] = *(const bf16x8*)(Bw + (((nt * 4 + kc) * 64 + lane) << 3));

  float br[8];
#pragma unroll
  for (int nt = 0; nt < 8; ++nt) br[nt] = bias[nt * 16 + c15];

  const int tiles = (M + 63) >> 6;
  for (int t = blockIdx.x; t < tiles; t += gridDim.x) {
    const int rbase = t * 64 + wid * 16;
    const int row = rbase + c15;
    bf16x8 a[4];
#pragma unroll
    for (int kc = 0; kc < 4; ++kc) {
      bf16x8 az = {};
      if (row < M) {
        const f32x4 v0 = *(const f32x4*)(x + (size_t)row * 128 + kc * 32 + kg * 8);
        const f32x4 v1 = *(const f32x4*)(x + (size_t)row * 128 + kc * 32 + kg * 8 + 4);
        az[0] = (short)f2bf(v0[0]); az[1] = (short)f2bf(v0[1]);
        az[2] = (short)f2bf(v0[2]); az[3] = (short)f2bf(v0[3]);
        az[4] = (short)f2bf(v1[0]); az[5] = (short)f2bf(v1[1]);
        az[6] = (short)f2bf(v1[2]); az[7] = (short)f2bf(v1[3]);
      }
      a[kc] = az;
    }
    f32x4 acc[8] = {};
#pragma unroll
    for (int kc = 0; kc < 4; ++kc)
#pragma unroll
      for (int nt = 0; nt < 8; ++nt)
        acc[nt] = __builtin_amdgcn_mfma_f32_16x16x32_bf16(a[kc], bf[nt][kc], acc[nt], 0, 0, 0);
#pragma unroll
    for (int r = 0; r < 4; ++r) {
      const int orow = rbase + kg * 4 + r;
      if (orow < M) {
#pragma unroll
        for (int nt = 0; nt < 8; ++nt)
          x[(size_t)orow * 128 + nt * 16 + c15] = silu_f(acc[nt][r] + br[nt]);
      }
    }
  }
}

__global__ void k_out(const float* __restrict__ x, const float* __restrict__ oW,
                      const float* __restrict__ ob, float* __restrict__ out, int M) {
  const int lane = threadIdx.x & 63;
  const int w = (int)((blockIdx.x * blockDim.x + threadIdx.x) >> 6);
  const int nw = (int)((gridDim.x * blockDim.x) >> 6);
  const float w0 = oW[lane], w1 = oW[64 + lane];
  const float obv = ob[0];
  for (int row = w; row < M; row += nw) {
    float a = x[(size_t)row * 128 + lane] * w0 + x[(size_t)row * 128 + 64 + lane] * w1;
#pragma unroll
    for (int m = 32; m; m >>= 1) a += __shfl_xor(a, m);
    if (lane == 0) out[row] = a + obv;
  }
}

// ---------------------------------------------------------------------------
extern "C" void kernel_launch(void* const* d_in, const int* in_sizes, int n_in,
                              void* d_out, int out_size, void* d_ws, size_t ws_size,
                              hipStream_t stream) {
  const float* h   = (const float*)d_in[0];
  const float* rb  = (const float*)d_in[1];
  const int*   ei  = (const int*)d_in[2];
  const float* rW1 = (const float*)d_in[3];
  const float* rb1 = (const float*)d_in[4];
  const float* rW2 = (const float*)d_in[5];
  const float* rb2 = (const float*)d_in[6];
  const float* dW0 = (const float*)d_in[7];
  const float* db0 = (const float*)d_in[8];
  const float* dW1 = (const float*)d_in[9];
  const float* db1 = (const float*)d_in[10];
  const float* dW2 = (const float*)d_in[11];
  const float* db2 = (const float*)d_in[12];
  const float* oW  = (const float*)d_in[13];
  const float* ob  = (const float*)d_in[14];

  const int NN = in_sizes[0] / 128;  // 50000 nodes
  const int E  = in_sizes[1] / 16;   // 600000 edges

  char* base = (char*)d_ws;
  size_t off = 0;
  auto alloc = [&](size_t bytes) {
    char* p = base + off;
    off += (bytes + 255) & ~(size_t)255;
    return p;
  };
  float* x            = (float*)alloc((size_t)NN * 128 * 4);  // fallback only
  unsigned short* wb  = (unsigned short*)alloc((size_t)69632 * 2);
  int* row_start      = (int*)alloc((size_t)(NN + 1) * 4);
  int* hist           = (int*)alloc((size_t)NN * 4);
  int* bump           = (int*)alloc((size_t)NN * 4);
  int* part           = (int*)alloc((size_t)64 * 4);
  unsigned short* Mb  = (unsigned short*)alloc((size_t)E * 256);
  const bool fits = off <= ws_size && NN <= 65535;

  const int ntiles = (E + 63) / 64;
  const int gE = (E + 255) / 256;
  const int nb = (NN + 1023) / 1024;

  if (fits) {
    k_prep<<<(69632 + NN + 255) / 256, 256, 0, stream>>>(rW1, rb1, rW2, dW0, dW1,
                                                         dW2, wb, hist, NN);
    k_hist<<<gE, 256, 0, stream>>>(ei, hist, E);
    k_scanA<<<nb, 1024, 0, stream>>>(hist, part, NN);
    k_scanC<<<nb, 1024, 0, stream>>>(hist, part, row_start, bump, NN, nb);
    const int eg = ntiles < 2048 ? ntiles : 2048;
    k_edge2<<<eg, 256, 0, stream>>>(rb, ei, h, wb, wb + 4096, rb2, bump, Mb, E, ntiles);
    const int gt = (NN + 127) / 128;
    k_gtile<<<gt, 512, 0, stream>>>(Mb, row_start, wb + 20480, db0, db1, db2,
                                    oW, ob, (float*)d_out, NN, gt);
  } else {
    k_prep<<<(69632 + 255) / 256, 256, 0, stream>>>(rW1, rb1, rW2, dW0, dW1,
                                                    dW2, wb, hist, 0);
    hipMemsetAsync(x, 0, (size_t)NN * 512, stream);
    const int eg = ntiles < 1024 ? ntiles : 1024;
    k_edge<<<eg, 256, 0, stream>>>(rb, ei, h, wb, wb + 4096, rb2, x, E, ntiles);
    k_dense<<<512, 256, 0, stream>>>(x, wb + 20480, db0, NN);
    k_dense<<<512, 256, 0, stream>>>(x, wb + 36864, db1, NN);
    k_dense<<<512, 256, 0, stream>>>(x, wb + 53248, db2, NN);
    k_out<<<512, 256, 0, stream>>>(x, oW, ob, (float*)d_out, NN);
  }
}